// Round 8
// baseline (107.753 us; speedup 1.0000x reference)
//
#include <hip/hip_runtime.h>
#include <math.h>

#define HH   128
#define WW   160
#define HWN  (HH*WW)      // 20480
#define NCF  32           // feature channels
#define NCD  8            // deps channels
#define ND   32           // depths
#define NV   3            // views
#define LAMBF 1.5f

typedef float f32x4 __attribute__((ext_vector_type(4)));
typedef float f32x2 __attribute__((ext_vector_type(2)));

__device__ __forceinline__ f32x2 pk_fma(f32x2 a, f32x2 b, f32x2 c) {
    f32x2 d;
    asm("v_pk_fma_f32 %0, %1, %2, %3" : "=v"(d) : "v"(a), "v"(b), "v"(c));
    return d;
}
__device__ __forceinline__ f32x2 pk_mul(f32x2 a, f32x2 b) {
    f32x2 d;
    asm("v_pk_mul_f32 %0, %1, %2" : "=v"(d) : "v"(a), "v"(b));
    return d;
}
__device__ __forceinline__ f32x2 pk_add(f32x2 a, f32x2 b) {
    f32x2 d;
    asm("v_pk_add_f32 %0, %1, %2" : "=v"(d) : "v"(a), "v"(b));
    return d;
}

// ---------------------------------------------------------------------------
// Prep: transpose (V,CH,H,W) -> (V,HW,CH) channel-last, float4 both sides.
// block(0,0,0)/thread0 also computes proj_v @ inv(proj_ref) -> projw[24].
// ---------------------------------------------------------------------------
template <int CH>
__device__ void transpose_tile(const float* __restrict__ src, float* __restrict__ dst,
                               float (*lds)[33], int tid) {
    for (int i = tid; i < CH*8; i += 256) {
        int c = i >> 3, xg = (i & 7) << 2;
        *(float4*)&lds[c][xg] = *(const float4*)(src + c*HWN + xg);
    }
    __syncthreads();
    for (int i = tid; i < 32*(CH/4); i += 256) {
        int xl = i / (CH/4), c4 = (i % (CH/4)) * 4;
        float4 t = make_float4(lds[c4][xl], lds[c4+1][xl], lds[c4+2][xl], lds[c4+3][xl]);
        *(float4*)(dst + xl*CH + c4) = t;
    }
}

__global__ __launch_bounds__(256) void prep_k(const float* __restrict__ feat,
                                              const float* __restrict__ deps,
                                              const float* __restrict__ proj,
                                              float* __restrict__ featT,
                                              float* __restrict__ depsT,
                                              float* __restrict__ projw) {
    if (blockIdx.x == 0 && blockIdx.y == 0 && blockIdx.z == 0 && threadIdx.x == 0) {
        float M00 = proj[0], M01 = proj[1], M02 = proj[2],  m0 = proj[3];
        float M10 = proj[4], M11 = proj[5], M12 = proj[6],  m1 = proj[7];
        float M20 = proj[8], M21 = proj[9], M22 = proj[10], m2 = proj[11];
        float c00 =  (M11*M22 - M12*M21);
        float c01 = -(M10*M22 - M12*M20);
        float c02 =  (M10*M21 - M11*M20);
        float det = M00*c00 + M01*c01 + M02*c02;
        float id  = 1.f / det;
        float i00 = c00*id, i01 = -(M01*M22 - M02*M21)*id, i02 =  (M01*M12 - M02*M11)*id;
        float i10 = c01*id, i11 =  (M00*M22 - M02*M20)*id, i12 = -(M00*M12 - M02*M10)*id;
        float i20 = c02*id, i21 = -(M00*M21 - M01*M20)*id, i22 =  (M00*M11 - M01*M10)*id;
        float t0 = -(i00*m0 + i01*m1 + i02*m2);
        float t1 = -(i10*m0 + i11*m1 + i12*m2);
        float t2 = -(i20*m0 + i21*m1 + i22*m2);
        #pragma unroll
        for (int v = 1; v < NV; v++) {
            const float* S = proj + v*16;
            float s00 = S[0], s01 = S[1], s02 = S[2],  st0 = S[3];
            float s10 = S[4], s11 = S[5], s12 = S[6],  st1 = S[7];
            float s20 = S[8], s21 = S[9], s22 = S[10], st2 = S[11];
            float* o = projw + (v-1)*12;
            o[0] = s00*i00 + s01*i10 + s02*i20;
            o[1] = s00*i01 + s01*i11 + s02*i21;
            o[2] = s00*i02 + s01*i12 + s02*i22;
            o[3] = s10*i00 + s11*i10 + s12*i20;
            o[4] = s10*i01 + s11*i11 + s12*i21;
            o[5] = s10*i02 + s11*i12 + s12*i22;
            o[6] = s20*i00 + s21*i10 + s22*i20;
            o[7] = s20*i01 + s21*i11 + s22*i21;
            o[8] = s20*i02 + s21*i12 + s22*i22;
            o[9]  = s00*t0 + s01*t1 + s02*t2 + st0;
            o[10] = s10*t0 + s11*t1 + s12*t2 + st1;
            o[11] = s20*t0 + s21*t1 + s22*t2 + st2;
        }
    }

    __shared__ float lds[NCF][33];
    const int z  = blockIdx.z;
    const int xb = blockIdx.x * 32;
    const int y  = blockIdx.y;
    if (z < NV) {
        transpose_tile<NCF>(feat + (size_t)(z*NCF)*HWN + y*WW + xb,
                            featT + (size_t)(z*HWN + y*WW + xb) * NCF,
                            lds, threadIdx.x);
    } else {
        transpose_tile<NCD>(deps + (size_t)((z - NV)*NCD)*HWN + y*WW + xb,
                            depsT + (size_t)((z - NV)*HWN + y*WW + xb) * NCD,
                            lds, threadIdx.x);
    }
}

// ---------------------------------------------------------------------------
// Main: block = 256 threads = 4 waves = 8 pixels x 32 depths.
// Wave w handles depths 8w..8w+7. Feat: lane = (pl<3b>, cg<3b>); lane cg owns
// bilinear setup for depth jj==cg; broadcast via shfl. Deps reuses the same
// setup via shfl (o_NCD = o_NCF >> 2). Inner math: v_pk_*_f32 packed FP32.
// grid = HWN/8 = 2560 blocks.
// ---------------------------------------------------------------------------
__global__ __launch_bounds__(256) void cost_volume_k(
    const float* __restrict__ featT,   // (V,HW,32)
    const float* __restrict__ depsT,   // (V,HW,8)
    const float* __restrict__ dvals,   // (D,HW)
    const float* __restrict__ regw,    // 40
    const float* __restrict__ pws,     // 24 (uniform -> scalar loads)
    float* __restrict__ out)
{
    __shared__ float cl [ND][9];
    __shared__ float dvl[ND][9];
    __shared__ float smax[8], sisum[8];

    const int t    = threadIdx.x;
    const int lane = t & 63;
    const int wid  = t >> 6;
    const int cg   = lane & 7;
    const int pl   = lane >> 3;
    const int pixg = blockIdx.x * 8 + pl;
    const int y    = pixg / WW;
    const int x    = pixg - y * WW;
    const float fx = (float)x, fy = (float)y;
    const int dbase = wid * 8;
    const int plbase = lane & 0x38;

    float RX[2], RY[2], RZ[2], T0[2], T1[2], T2[2];
    #pragma unroll
    for (int v = 0; v < 2; v++) {
        const float* q = pws + v*12;
        RX[v] = q[0]*fx + q[1]*fy + q[2];
        RY[v] = q[3]*fx + q[4]*fy + q[5];
        RZ[v] = q[6]*fx + q[7]*fy + q[8];
        T0[v] = q[9]; T1[v] = q[10]; T2[v] = q[11];
    }

    // lane cg owns the bilinear setup for depth jj==cg (both views), NCF units
    float SW00[2], SW10[2], SW01[2], SW11[2];
    int   SO00[2], SO10[2], SO01[2], SO11[2];
    {
        float dvv_own = dvals[(dbase + cg)*HWN + pixg];
        dvl[dbase + cg][pl] = dvv_own;
        #pragma unroll
        for (int v = 0; v < 2; v++) {
            float pz = RZ[v]*dvv_own + T2[v];
            float iz = __builtin_amdgcn_rcpf(pz);
            float px = (RX[v]*dvv_own + T0[v]) * iz;
            float py = (RY[v]*dvv_own + T1[v]) * iz;
            float x0f = floorf(px), y0f = floorf(py);
            int x0 = (int)x0f, y0 = (int)y0f;
            float wx = px - x0f, wy = py - y0f;
            float omx = 1.f - wx, omy = 1.f - wy;
            bool vx0 = (x0 >= 0) & (x0 < WW);
            bool vx1 = (x0+1 >= 0) & (x0+1 < WW);
            bool vy0 = (y0 >= 0) & (y0 < HH);
            bool vy1 = (y0+1 >= 0) & (y0+1 < HH);
            SW00[v] = (vx0 && vy0) ? omx*omy : 0.f;
            SW10[v] = (vx1 && vy0) ? wx*omy  : 0.f;
            SW01[v] = (vx0 && vy1) ? omx*wy  : 0.f;
            SW11[v] = (vx1 && vy1) ? wx*wy   : 0.f;
            int xc0 = min(max(x0,   0), WW-1);
            int xc1 = min(max(x0+1, 0), WW-1);
            int yc0 = min(max(y0,   0), HH-1);
            int yc1 = min(max(y0+1, 0), HH-1);
            SO00[v] = (yc0*WW + xc0)*NCF;
            SO10[v] = (yc0*WW + xc1)*NCF;
            SO01[v] = (yc1*WW + xc0)*NCF;
            SO11[v] = (yc1*WW + xc1)*NCF;
        }
    }

    // ================== FEAT PHASE ==================
    {
        const f32x4 r4 = *(const f32x4*)(featT + (size_t)pixg*NCF + cg*4);
        const f32x4 w4 = *(const f32x4*)(regw + cg*4);
        const f32x2 wca_l  = w4.lo * (1.f/3.f), wca_h  = w4.hi * (1.f/3.f);
        const f32x2 nwcb_l = w4.lo * (-1.f/9.f), nwcb_h = w4.hi * (-1.f/9.f);
        const f32x2 r_l = r4.lo, r_h = r4.hi;
        const f32x2 r2_l = r_l*r_l, r2_h = r_h*r_h;
        const float* b1 = featT + (size_t)1*HWN*NCF + cg*4;
        const float* b2 = featT + (size_t)2*HWN*NCF + cg*4;

        #pragma unroll 2
        for (int jj = 0; jj < 8; jj++) {
            const int src = plbase | jj;
            f32x2 s_l = r_l, s_h = r_h;
            f32x2 q_l = r2_l, q_h = r2_h;

            #pragma unroll
            for (int v = 0; v < 2; v++) {
                float W00 = __shfl(SW00[v], src, 64);
                float W10 = __shfl(SW10[v], src, 64);
                float W01 = __shfl(SW01[v], src, 64);
                float W11 = __shfl(SW11[v], src, 64);
                int   o00 = __shfl(SO00[v], src, 64);
                int   o10 = __shfl(SO10[v], src, 64);
                int   o01 = __shfl(SO01[v], src, 64);
                int   o11 = __shfl(SO11[v], src, 64);
                const float* b = v ? b2 : b1;
                f32x4 f00 = *(const f32x4*)(b + o00);
                f32x4 f10 = *(const f32x4*)(b + o10);
                f32x4 f01 = *(const f32x4*)(b + o01);
                f32x4 f11 = *(const f32x4*)(b + o11);
                f32x2 W00p = {W00, W00}, W10p = {W10, W10};
                f32x2 W01p = {W01, W01}, W11p = {W11, W11};
                f32x2 wv_l = pk_mul(f00.lo, W00p);
                wv_l = pk_fma(f10.lo, W10p, wv_l);
                wv_l = pk_fma(f01.lo, W01p, wv_l);
                wv_l = pk_fma(f11.lo, W11p, wv_l);
                f32x2 wv_h = pk_mul(f00.hi, W00p);
                wv_h = pk_fma(f10.hi, W10p, wv_h);
                wv_h = pk_fma(f01.hi, W01p, wv_h);
                wv_h = pk_fma(f11.hi, W11p, wv_h);
                s_l = pk_add(s_l, wv_l); q_l = pk_fma(wv_l, wv_l, q_l);
                s_h = pk_add(s_h, wv_h); q_h = pk_fma(wv_h, wv_h, q_h);
            }
            f32x2 t_l = pk_mul(q_l, wca_l);
            t_l = pk_fma(pk_mul(s_l, s_l), nwcb_l, t_l);
            f32x2 t_h = pk_mul(q_h, wca_h);
            t_h = pk_fma(pk_mul(s_h, s_h), nwcb_h, t_h);
            float part = (t_l.x + t_l.y) + (t_h.x + t_h.y);
            part += __shfl_xor(part, 1);
            part += __shfl_xor(part, 2);
            part += __shfl_xor(part, 4);
            if (cg == jj) cl[dbase + jj][pl] = part;
        }
    }

    // ================== DEPS PHASE ==================
    // lane = (pl<3b>, dsub<2b>, cgd<1b>); reuse feat setup via shfl, >>2.
    {
        const int cgd  = lane & 1;
        const int dsub = (lane >> 1) & 3;
        const f32x4 r4 = *(const f32x4*)(depsT + (size_t)pixg*NCD + cgd*4);
        const f32x4 w4 = *(const f32x4*)(regw + NCF + cgd*4);
        const f32x2 wca_l  = w4.lo * (1.f/3.f), wca_h  = w4.hi * (1.f/3.f);
        const f32x2 nwcb_l = w4.lo * (-1.f/9.f), nwcb_h = w4.hi * (-1.f/9.f);
        const f32x2 r_l = r4.lo, r_h = r4.hi;
        const f32x2 r2_l = r_l*r_l, r2_h = r_h*r_h;
        const float* b1 = depsT + (size_t)1*HWN*NCD + cgd*4;
        const float* b2 = depsT + (size_t)2*HWN*NCD + cgd*4;

        #pragma unroll
        for (int i = 0; i < 2; i++) {
            const int jj = dsub + 4*i;
            const int d  = dbase + jj;
            const int src = plbase | jj;
            f32x2 s_l = r_l, s_h = r_h;
            f32x2 q_l = r2_l, q_h = r2_h;

            #pragma unroll
            for (int v = 0; v < 2; v++) {
                float W00 = __shfl(SW00[v], src, 64);
                float W10 = __shfl(SW10[v], src, 64);
                float W01 = __shfl(SW01[v], src, 64);
                float W11 = __shfl(SW11[v], src, 64);
                int   o00 = __shfl(SO00[v], src, 64) >> 2;
                int   o10 = __shfl(SO10[v], src, 64) >> 2;
                int   o01 = __shfl(SO01[v], src, 64) >> 2;
                int   o11 = __shfl(SO11[v], src, 64) >> 2;
                const float* b = v ? b2 : b1;
                f32x4 f00 = *(const f32x4*)(b + o00);
                f32x4 f10 = *(const f32x4*)(b + o10);
                f32x4 f01 = *(const f32x4*)(b + o01);
                f32x4 f11 = *(const f32x4*)(b + o11);
                f32x2 W00p = {W00, W00}, W10p = {W10, W10};
                f32x2 W01p = {W01, W01}, W11p = {W11, W11};
                f32x2 wv_l = pk_mul(f00.lo, W00p);
                wv_l = pk_fma(f10.lo, W10p, wv_l);
                wv_l = pk_fma(f01.lo, W01p, wv_l);
                wv_l = pk_fma(f11.lo, W11p, wv_l);
                f32x2 wv_h = pk_mul(f00.hi, W00p);
                wv_h = pk_fma(f10.hi, W10p, wv_h);
                wv_h = pk_fma(f01.hi, W01p, wv_h);
                wv_h = pk_fma(f11.hi, W11p, wv_h);
                s_l = pk_add(s_l, wv_l); q_l = pk_fma(wv_l, wv_l, q_l);
                s_h = pk_add(s_h, wv_h); q_h = pk_fma(wv_h, wv_h, q_h);
            }
            f32x2 t_l = pk_mul(q_l, wca_l);
            t_l = pk_fma(pk_mul(s_l, s_l), nwcb_l, t_l);
            f32x2 t_h = pk_mul(q_h, wca_h);
            t_h = pk_fma(pk_mul(s_h, s_h), nwcb_h, t_h);
            float part = (t_l.x + t_l.y) + (t_h.x + t_h.y);
            part += __shfl_xor(part, 1);
            if (cgd == 0) cl[d][pl] += part;   // disjoint d-ranges per wave
        }
    }
    __syncthreads();

    // ================== SOFTMAX + MOMENTS ==================
    if (t < 8) {
        const int plx  = t;
        const int pixo = blockIdx.x * 8 + plx;
        float m = -1e30f;
        #pragma unroll
        for (int d = 0; d < ND; d++) m = fmaxf(m, cl[d][plx]);
        float sum = 0.f, pd = 0.f, pd2 = 0.f;
        #pragma unroll
        for (int d = 0; d < ND; d++) {
            float e   = __expf(cl[d][plx] - m);
            float dvv = dvl[d][plx];
            sum += e;
            pd  = fmaf(e, dvv, pd);
            pd2 = fmaf(e, dvv*dvv, pd2);
        }
        float isum  = 1.f / sum;
        float depth = pd * isum;
        float sv    = pd2 * isum - depth*depth;
        float ev    = LAMBF * sqrtf(fmaxf(sv, 0.f));
        smax[plx]  = m;
        sisum[plx] = isum;
        out[pixo]       = depth;
        out[HWN + pixo] = ev;
    }
    __syncthreads();
    {
        const int plx  = t & 7;
        const int dd   = t >> 3;
        const int pixo = blockIdx.x * 8 + plx;
        out[2*HWN + dd*HWN + pixo] = __expf(cl[dd][plx] - smax[plx]) * sisum[plx];
    }
}

// ---------------------------------------------------------------------------
extern "C" void kernel_launch(void* const* d_in, const int* in_sizes, int n_in,
                              void* d_out, int out_size, void* d_ws, size_t ws_size,
                              hipStream_t stream) {
    const float* features = (const float*)d_in[0];   // (V,1,32,H,W)
    const float* deps     = (const float*)d_in[1];   // (V,1,8,H,W)
    const float* proj     = (const float*)d_in[2];   // (1,V,4,4)
    const float* dvals    = (const float*)d_in[3];   // (1,D,H,W)
    const float* regw     = (const float*)d_in[4];   // (1,40)

    float* ws    = (float*)d_ws;
    float* projw = ws;                         // 24 floats (64 reserved)
    float* featT = ws + 64;                    // 3*HW*32
    float* depsT = featT + (size_t)NV*HWN*NCF; // 3*HW*8

    dim3 tg(WW/32, HH, 2*NV);
    prep_k<<<tg, 256, 0, stream>>>(features, deps, proj, featT, depsT, projw);

    cost_volume_k<<<HWN/8, 256, 0, stream>>>(featT, depsT, dvals, regw, projw,
                                             (float*)d_out);
}

// Round 9
// 103.046 us; speedup vs baseline: 1.0457x; 1.0457x over previous
//
#include <hip/hip_runtime.h>
#include <hip/hip_fp16.h>
#include <math.h>

#define HH   128
#define WW   160
#define HWN  (HH*WW)      // 20480
#define NCF  32           // feature channels
#define NCD  8            // deps channels
#define ND   32           // depths
#define NV   3            // views
#define LAMBF 1.5f

// ---------------------------------------------------------------------------
// Prep: transpose (V,CH,H,W) f32 -> (V,HW,CH) fp16 channel-last.
// block(0,0,0)/thread0 also computes proj_v @ inv(proj_ref) -> projw[24].
// grid = (W/32, H, 6): z<3 feat views, z>=3 deps views.
// ---------------------------------------------------------------------------
template <int CH>
__device__ void transpose_tile(const float* __restrict__ src, __half* __restrict__ dst,
                               float (*lds)[33], int tid) {
    for (int i = tid; i < CH*8; i += 256) {
        int c = i >> 3, xg = (i & 7) << 2;
        *(float4*)&lds[c][xg] = *(const float4*)(src + c*HWN + xg);
    }
    __syncthreads();
    for (int i = tid; i < 32*(CH/4); i += 256) {
        int xl = i / (CH/4), c4 = (i % (CH/4)) * 4;
        __half2 h0 = __floats2half2_rn(lds[c4][xl],   lds[c4+1][xl]);
        __half2 h1 = __floats2half2_rn(lds[c4+2][xl], lds[c4+3][xl]);
        uint2 u; u.x = *(unsigned*)&h0; u.y = *(unsigned*)&h1;
        *(uint2*)(dst + xl*CH + c4) = u;
    }
}

__global__ __launch_bounds__(256) void prep_k(const float* __restrict__ feat,
                                              const float* __restrict__ deps,
                                              const float* __restrict__ proj,
                                              __half* __restrict__ featH,
                                              __half* __restrict__ depsH,
                                              float* __restrict__ projw) {
    if (blockIdx.x == 0 && blockIdx.y == 0 && blockIdx.z == 0 && threadIdx.x == 0) {
        float M00 = proj[0], M01 = proj[1], M02 = proj[2],  m0 = proj[3];
        float M10 = proj[4], M11 = proj[5], M12 = proj[6],  m1 = proj[7];
        float M20 = proj[8], M21 = proj[9], M22 = proj[10], m2 = proj[11];
        float c00 =  (M11*M22 - M12*M21);
        float c01 = -(M10*M22 - M12*M20);
        float c02 =  (M10*M21 - M11*M20);
        float det = M00*c00 + M01*c01 + M02*c02;
        float id  = 1.f / det;
        float i00 = c00*id, i01 = -(M01*M22 - M02*M21)*id, i02 =  (M01*M12 - M02*M11)*id;
        float i10 = c01*id, i11 =  (M00*M22 - M02*M20)*id, i12 = -(M00*M12 - M02*M10)*id;
        float i20 = c02*id, i21 = -(M00*M21 - M01*M20)*id, i22 =  (M00*M11 - M01*M10)*id;
        float t0 = -(i00*m0 + i01*m1 + i02*m2);
        float t1 = -(i10*m0 + i11*m1 + i12*m2);
        float t2 = -(i20*m0 + i21*m1 + i22*m2);
        #pragma unroll
        for (int v = 1; v < NV; v++) {
            const float* S = proj + v*16;
            float s00 = S[0], s01 = S[1], s02 = S[2],  st0 = S[3];
            float s10 = S[4], s11 = S[5], s12 = S[6],  st1 = S[7];
            float s20 = S[8], s21 = S[9], s22 = S[10], st2 = S[11];
            float* o = projw + (v-1)*12;
            o[0] = s00*i00 + s01*i10 + s02*i20;
            o[1] = s00*i01 + s01*i11 + s02*i21;
            o[2] = s00*i02 + s01*i12 + s02*i22;
            o[3] = s10*i00 + s11*i10 + s12*i20;
            o[4] = s10*i01 + s11*i11 + s12*i21;
            o[5] = s10*i02 + s11*i12 + s12*i22;
            o[6] = s20*i00 + s21*i10 + s22*i20;
            o[7] = s20*i01 + s21*i11 + s22*i21;
            o[8] = s20*i02 + s21*i12 + s22*i22;
            o[9]  = s00*t0 + s01*t1 + s02*t2 + st0;
            o[10] = s10*t0 + s11*t1 + s12*t2 + st1;
            o[11] = s20*t0 + s21*t1 + s22*t2 + st2;
        }
    }

    __shared__ float lds[NCF][33];
    const int z  = blockIdx.z;
    const int xb = blockIdx.x * 32;
    const int y  = blockIdx.y;
    if (z < NV) {
        transpose_tile<NCF>(feat + (size_t)(z*NCF)*HWN + y*WW + xb,
                            featH + (size_t)(z*HWN + y*WW + xb) * NCF,
                            lds, threadIdx.x);
    } else {
        transpose_tile<NCD>(deps + (size_t)((z - NV)*NCD)*HWN + y*WW + xb,
                            depsH + (size_t)((z - NV)*HWN + y*WW + xb) * NCD,
                            lds, threadIdx.x);
    }
}

// ---------------------------------------------------------------------------
// Main: block = 256 threads = 4 waves = 8 pixels x 32 depths.
// Wave w handles depths 8w..8w+7. Feat: lane = (pl<3b>, cg<3b>); lane cg owns
// bilinear setup for depth jj==cg; weights pre-packed as broadcast half2 and
// broadcast via shfl. Interpolation in v_pk_fma_f16; variance accum in f32.
// Deps reuses feat setup via shfl (o_NCD = o_NCF >> 2).
// grid = HWN/8 = 2560 blocks.
// ---------------------------------------------------------------------------
__global__ __launch_bounds__(256) void cost_volume_k(
    const __half* __restrict__ featH,  // (V,HW,32) fp16
    const __half* __restrict__ depsH,  // (V,HW,8)  fp16
    const float* __restrict__ dvals,   // (D,HW)
    const float* __restrict__ regw,    // 40
    const float* __restrict__ pws,     // 24 (uniform -> scalar loads)
    float* __restrict__ out)
{
    __shared__ float cl [ND][9];
    __shared__ float dvl[ND][9];
    __shared__ float smax[8], sisum[8];

    const int t    = threadIdx.x;
    const int lane = t & 63;
    const int wid  = t >> 6;
    const int cg   = lane & 7;
    const int pl   = lane >> 3;
    const int pixg = blockIdx.x * 8 + pl;
    const int y    = pixg / WW;
    const int x    = pixg - y * WW;
    const float fx = (float)x, fy = (float)y;
    const int dbase = wid * 8;
    const int plbase = lane & 0x38;

    float RX[2], RY[2], RZ[2], T0[2], T1[2], T2[2];
    #pragma unroll
    for (int v = 0; v < 2; v++) {
        const float* q = pws + v*12;
        RX[v] = q[0]*fx + q[1]*fy + q[2];
        RY[v] = q[3]*fx + q[4]*fy + q[5];
        RZ[v] = q[6]*fx + q[7]*fy + q[8];
        T0[v] = q[9]; T1[v] = q[10]; T2[v] = q[11];
    }

    // lane cg owns bilinear setup for depth jj==cg (both views); weights
    // stored as broadcast half2 bit-packed into int for cheap shfl.
    int SW00[2], SW10[2], SW01[2], SW11[2];
    int SO00[2], SO10[2], SO01[2], SO11[2];
    {
        float dvv_own = dvals[(dbase + cg)*HWN + pixg];
        dvl[dbase + cg][pl] = dvv_own;
        #pragma unroll
        for (int v = 0; v < 2; v++) {
            float pz = RZ[v]*dvv_own + T2[v];
            float iz = __builtin_amdgcn_rcpf(pz);
            float px = (RX[v]*dvv_own + T0[v]) * iz;
            float py = (RY[v]*dvv_own + T1[v]) * iz;
            float x0f = floorf(px), y0f = floorf(py);
            int x0 = (int)x0f, y0 = (int)y0f;
            float wx = px - x0f, wy = py - y0f;
            float omx = 1.f - wx, omy = 1.f - wy;
            bool vx0 = (x0 >= 0) & (x0 < WW);
            bool vx1 = (x0+1 >= 0) & (x0+1 < WW);
            bool vy0 = (y0 >= 0) & (y0 < HH);
            bool vy1 = (y0+1 >= 0) & (y0+1 < HH);
            float W00 = (vx0 && vy0) ? omx*omy : 0.f;
            float W10 = (vx1 && vy0) ? wx*omy  : 0.f;
            float W01 = (vx0 && vy1) ? omx*wy  : 0.f;
            float W11 = (vx1 && vy1) ? wx*wy   : 0.f;
            __half2 h;
            h = __float2half2_rn(W00); SW00[v] = *(int*)&h;
            h = __float2half2_rn(W10); SW10[v] = *(int*)&h;
            h = __float2half2_rn(W01); SW01[v] = *(int*)&h;
            h = __float2half2_rn(W11); SW11[v] = *(int*)&h;
            int xc0 = min(max(x0,   0), WW-1);
            int xc1 = min(max(x0+1, 0), WW-1);
            int yc0 = min(max(y0,   0), HH-1);
            int yc1 = min(max(y0+1, 0), HH-1);
            SO00[v] = (yc0*WW + xc0)*NCF;
            SO10[v] = (yc0*WW + xc1)*NCF;
            SO01[v] = (yc1*WW + xc0)*NCF;
            SO11[v] = (yc1*WW + xc1)*NCF;
        }
    }

    // gather helper: 4 fp16 channels bilinear -> 2 f32 pairs accumulated
    #define INTERP(BPTR, O00, O10, O01, O11, W00p, W10p, W01p, W11p)          \
        {                                                                      \
            uint2 u00 = *(const uint2*)(BPTR + O00);                           \
            uint2 u10 = *(const uint2*)(BPTR + O10);                           \
            uint2 u01 = *(const uint2*)(BPTR + O01);                           \
            uint2 u11 = *(const uint2*)(BPTR + O11);                           \
            __half2 wva = __hmul2(*(__half2*)&u00.x, W00p);                    \
            wva = __hfma2(*(__half2*)&u10.x, W10p, wva);                       \
            wva = __hfma2(*(__half2*)&u01.x, W01p, wva);                       \
            wva = __hfma2(*(__half2*)&u11.x, W11p, wva);                       \
            __half2 wvb = __hmul2(*(__half2*)&u00.y, W00p);                    \
            wvb = __hfma2(*(__half2*)&u10.y, W10p, wvb);                       \
            wvb = __hfma2(*(__half2*)&u01.y, W01p, wvb);                       \
            wvb = __hfma2(*(__half2*)&u11.y, W11p, wvb);                       \
            float2 fa = __half22float2(wva);                                   \
            float2 fb = __half22float2(wvb);                                   \
            s0 += fa.x; q0 = fmaf(fa.x, fa.x, q0);                             \
            s1 += fa.y; q1 = fmaf(fa.y, fa.y, q1);                             \
            s2 += fb.x; q2 = fmaf(fb.x, fb.x, q2);                             \
            s3 += fb.y; q3 = fmaf(fb.y, fb.y, q3);                             \
        }

    // ================== FEAT PHASE ==================
    {
        // ref values (fp16) -> f32 once
        uint2 ur = *(const uint2*)(featH + (size_t)pixg*NCF + cg*4);
        float2 ra = __half22float2(*(__half2*)&ur.x);
        float2 rb = __half22float2(*(__half2*)&ur.y);
        const float rx0 = ra.x, rx1 = ra.y, rx2 = rb.x, rx3 = rb.y;
        const float4 w4 = *(const float4*)(regw + cg*4);
        const float wca0 = w4.x*(1.f/3.f), wca1 = w4.y*(1.f/3.f),
                    wca2 = w4.z*(1.f/3.f), wca3 = w4.w*(1.f/3.f);
        const float wcb0 = w4.x*(1.f/9.f), wcb1 = w4.y*(1.f/9.f),
                    wcb2 = w4.z*(1.f/9.f), wcb3 = w4.w*(1.f/9.f);
        const __half* b1 = featH + (size_t)1*HWN*NCF + cg*4;
        const __half* b2 = featH + (size_t)2*HWN*NCF + cg*4;

        #pragma unroll 2
        for (int jj = 0; jj < 8; jj++) {
            const int src = plbase | jj;
            float s0 = rx0, s1 = rx1, s2 = rx2, s3 = rx3;
            float q0 = rx0*rx0, q1 = rx1*rx1, q2 = rx2*rx2, q3 = rx3*rx3;

            #pragma unroll
            for (int v = 0; v < 2; v++) {
                int w00i = __shfl(SW00[v], src, 64);
                int w10i = __shfl(SW10[v], src, 64);
                int w01i = __shfl(SW01[v], src, 64);
                int w11i = __shfl(SW11[v], src, 64);
                int o00  = __shfl(SO00[v], src, 64);
                int o10  = __shfl(SO10[v], src, 64);
                int o01  = __shfl(SO01[v], src, 64);
                int o11  = __shfl(SO11[v], src, 64);
                __half2 W00p = *(__half2*)&w00i, W10p = *(__half2*)&w10i;
                __half2 W01p = *(__half2*)&w01i, W11p = *(__half2*)&w11i;
                const __half* b = v ? b2 : b1;
                INTERP(b, o00, o10, o01, o11, W00p, W10p, W01p, W11p)
            }
            float part = wca0*q0 - wcb0*s0*s0;
            part = fmaf(wca1, q1, part); part = fmaf(-wcb1, s1*s1, part);
            part = fmaf(wca2, q2, part); part = fmaf(-wcb2, s2*s2, part);
            part = fmaf(wca3, q3, part); part = fmaf(-wcb3, s3*s3, part);
            part += __shfl_xor(part, 1);
            part += __shfl_xor(part, 2);
            part += __shfl_xor(part, 4);
            if (cg == jj) cl[dbase + jj][pl] = part;
        }
    }

    // ================== DEPS PHASE ==================
    // lane = (pl<3b>, dsub<2b>, cgd<1b>); reuse feat setup via shfl, >>2.
    {
        const int cgd  = lane & 1;
        const int dsub = (lane >> 1) & 3;
        uint2 ur = *(const uint2*)(depsH + (size_t)pixg*NCD + cgd*4);
        float2 ra = __half22float2(*(__half2*)&ur.x);
        float2 rb = __half22float2(*(__half2*)&ur.y);
        const float rx0 = ra.x, rx1 = ra.y, rx2 = rb.x, rx3 = rb.y;
        const float4 w4 = *(const float4*)(regw + NCF + cgd*4);
        const float wca0 = w4.x*(1.f/3.f), wca1 = w4.y*(1.f/3.f),
                    wca2 = w4.z*(1.f/3.f), wca3 = w4.w*(1.f/3.f);
        const float wcb0 = w4.x*(1.f/9.f), wcb1 = w4.y*(1.f/9.f),
                    wcb2 = w4.z*(1.f/9.f), wcb3 = w4.w*(1.f/9.f);
        const __half* b1 = depsH + (size_t)1*HWN*NCD + cgd*4;
        const __half* b2 = depsH + (size_t)2*HWN*NCD + cgd*4;

        #pragma unroll
        for (int i = 0; i < 2; i++) {
            const int jj = dsub + 4*i;
            const int d  = dbase + jj;
            const int src = plbase | jj;
            float s0 = rx0, s1 = rx1, s2 = rx2, s3 = rx3;
            float q0 = rx0*rx0, q1 = rx1*rx1, q2 = rx2*rx2, q3 = rx3*rx3;

            #pragma unroll
            for (int v = 0; v < 2; v++) {
                int w00i = __shfl(SW00[v], src, 64);
                int w10i = __shfl(SW10[v], src, 64);
                int w01i = __shfl(SW01[v], src, 64);
                int w11i = __shfl(SW11[v], src, 64);
                int o00  = __shfl(SO00[v], src, 64) >> 2;
                int o10  = __shfl(SO10[v], src, 64) >> 2;
                int o01  = __shfl(SO01[v], src, 64) >> 2;
                int o11  = __shfl(SO11[v], src, 64) >> 2;
                __half2 W00p = *(__half2*)&w00i, W10p = *(__half2*)&w10i;
                __half2 W01p = *(__half2*)&w01i, W11p = *(__half2*)&w11i;
                const __half* b = v ? b2 : b1;
                INTERP(b, o00, o10, o01, o11, W00p, W10p, W01p, W11p)
            }
            float part = wca0*q0 - wcb0*s0*s0;
            part = fmaf(wca1, q1, part); part = fmaf(-wcb1, s1*s1, part);
            part = fmaf(wca2, q2, part); part = fmaf(-wcb2, s2*s2, part);
            part = fmaf(wca3, q3, part); part = fmaf(-wcb3, s3*s3, part);
            part += __shfl_xor(part, 1);
            if (cgd == 0) cl[d][pl] += part;   // disjoint d-ranges per wave
        }
    }
    __syncthreads();

    // ================== SOFTMAX + MOMENTS ==================
    if (t < 8) {
        const int plx  = t;
        const int pixo = blockIdx.x * 8 + plx;
        float m = -1e30f;
        #pragma unroll
        for (int d = 0; d < ND; d++) m = fmaxf(m, cl[d][plx]);
        float sum = 0.f, pd = 0.f, pd2 = 0.f;
        #pragma unroll
        for (int d = 0; d < ND; d++) {
            float e   = __expf(cl[d][plx] - m);
            float dvv = dvl[d][plx];
            sum += e;
            pd  = fmaf(e, dvv, pd);
            pd2 = fmaf(e, dvv*dvv, pd2);
        }
        float isum  = 1.f / sum;
        float depth = pd * isum;
        float sv    = pd2 * isum - depth*depth;
        float ev    = LAMBF * sqrtf(fmaxf(sv, 0.f));
        smax[plx]  = m;
        sisum[plx] = isum;
        out[pixo]       = depth;
        out[HWN + pixo] = ev;
    }
    __syncthreads();
    {
        const int plx  = t & 7;
        const int dd   = t >> 3;
        const int pixo = blockIdx.x * 8 + plx;
        out[2*HWN + dd*HWN + pixo] = __expf(cl[dd][plx] - smax[plx]) * sisum[plx];
    }
}

// ---------------------------------------------------------------------------
extern "C" void kernel_launch(void* const* d_in, const int* in_sizes, int n_in,
                              void* d_out, int out_size, void* d_ws, size_t ws_size,
                              hipStream_t stream) {
    const float* features = (const float*)d_in[0];   // (V,1,32,H,W)
    const float* deps     = (const float*)d_in[1];   // (V,1,8,H,W)
    const float* proj     = (const float*)d_in[2];   // (1,V,4,4)
    const float* dvals    = (const float*)d_in[3];   // (1,D,H,W)
    const float* regw     = (const float*)d_in[4];   // (1,40)

    float*  ws    = (float*)d_ws;
    float*  projw = ws;                              // 24 floats (64 reserved)
    __half* featH = (__half*)(ws + 64);              // 3*HW*32 halves
    __half* depsH = featH + (size_t)NV*HWN*NCF;      // 3*HW*8 halves

    dim3 tg(WW/32, HH, 2*NV);
    prep_k<<<tg, 256, 0, stream>>>(features, deps, proj, featH, depsH, projw);

    cost_volume_k<<<HWN/8, 256, 0, stream>>>(featH, depsH, dvals, regw, projw,
                                             (float*)d_out);
}

// Round 10
// 94.308 us; speedup vs baseline: 1.1426x; 1.0927x over previous
//
#include <hip/hip_runtime.h>
#include <hip/hip_fp16.h>
#include <math.h>

#define HH   128
#define WW   160
#define HWN  (HH*WW)      // 20480
#define NCF  32           // feature channels
#define NCD  8            // deps channels
#define ND   32           // depths
#define NV   3            // views
#define LAMBF 1.5f

// ---------------------------------------------------------------------------
// Prep: transpose (V,CH,H,W) f32 -> (V,HW,CH) fp16 channel-last.
// block(0,0,0)/thread0 also computes proj_v @ inv(proj_ref) -> projw[24].
// ---------------------------------------------------------------------------
template <int CH>
__device__ void transpose_tile(const float* __restrict__ src, __half* __restrict__ dst,
                               float (*lds)[33], int tid) {
    for (int i = tid; i < CH*8; i += 256) {
        int c = i >> 3, xg = (i & 7) << 2;
        *(float4*)&lds[c][xg] = *(const float4*)(src + c*HWN + xg);
    }
    __syncthreads();
    for (int i = tid; i < 32*(CH/4); i += 256) {
        int xl = i / (CH/4), c4 = (i % (CH/4)) * 4;
        __half2 h0 = __floats2half2_rn(lds[c4][xl],   lds[c4+1][xl]);
        __half2 h1 = __floats2half2_rn(lds[c4+2][xl], lds[c4+3][xl]);
        uint2 u; u.x = *(unsigned*)&h0; u.y = *(unsigned*)&h1;
        *(uint2*)(dst + xl*CH + c4) = u;
    }
}

__global__ __launch_bounds__(256) void prep_k(const float* __restrict__ feat,
                                              const float* __restrict__ deps,
                                              const float* __restrict__ proj,
                                              __half* __restrict__ featH,
                                              __half* __restrict__ depsH,
                                              float* __restrict__ projw) {
    if (blockIdx.x == 0 && blockIdx.y == 0 && blockIdx.z == 0 && threadIdx.x == 0) {
        float M00 = proj[0], M01 = proj[1], M02 = proj[2],  m0 = proj[3];
        float M10 = proj[4], M11 = proj[5], M12 = proj[6],  m1 = proj[7];
        float M20 = proj[8], M21 = proj[9], M22 = proj[10], m2 = proj[11];
        float c00 =  (M11*M22 - M12*M21);
        float c01 = -(M10*M22 - M12*M20);
        float c02 =  (M10*M21 - M11*M20);
        float det = M00*c00 + M01*c01 + M02*c02;
        float id  = 1.f / det;
        float i00 = c00*id, i01 = -(M01*M22 - M02*M21)*id, i02 =  (M01*M12 - M02*M11)*id;
        float i10 = c01*id, i11 =  (M00*M22 - M02*M20)*id, i12 = -(M00*M12 - M02*M10)*id;
        float i20 = c02*id, i21 = -(M00*M21 - M01*M20)*id, i22 =  (M00*M11 - M01*M10)*id;
        float t0 = -(i00*m0 + i01*m1 + i02*m2);
        float t1 = -(i10*m0 + i11*m1 + i12*m2);
        float t2 = -(i20*m0 + i21*m1 + i22*m2);
        #pragma unroll
        for (int v = 1; v < NV; v++) {
            const float* S = proj + v*16;
            float s00 = S[0], s01 = S[1], s02 = S[2],  st0 = S[3];
            float s10 = S[4], s11 = S[5], s12 = S[6],  st1 = S[7];
            float s20 = S[8], s21 = S[9], s22 = S[10], st2 = S[11];
            float* o = projw + (v-1)*12;
            o[0] = s00*i00 + s01*i10 + s02*i20;
            o[1] = s00*i01 + s01*i11 + s02*i21;
            o[2] = s00*i02 + s01*i12 + s02*i22;
            o[3] = s10*i00 + s11*i10 + s12*i20;
            o[4] = s10*i01 + s11*i11 + s12*i21;
            o[5] = s10*i02 + s11*i12 + s12*i22;
            o[6] = s20*i00 + s21*i10 + s22*i20;
            o[7] = s20*i01 + s21*i11 + s22*i21;
            o[8] = s20*i02 + s21*i12 + s22*i22;
            o[9]  = s00*t0 + s01*t1 + s02*t2 + st0;
            o[10] = s10*t0 + s11*t1 + s12*t2 + st1;
            o[11] = s20*t0 + s21*t1 + s22*t2 + st2;
        }
    }

    __shared__ float lds[NCF][33];
    const int z  = blockIdx.z;
    const int xb = blockIdx.x * 32;
    const int y  = blockIdx.y;
    if (z < NV) {
        transpose_tile<NCF>(feat + (size_t)(z*NCF)*HWN + y*WW + xb,
                            featH + (size_t)(z*HWN + y*WW + xb) * NCF,
                            lds, threadIdx.x);
    } else {
        transpose_tile<NCD>(deps + (size_t)((z - NV)*NCD)*HWN + y*WW + xb,
                            depsH + (size_t)((z - NV)*HWN + y*WW + xb) * NCD,
                            lds, threadIdx.x);
    }
}

// ---------------------------------------------------------------------------
// Main: block = 256 threads = 4 waves = 8 pixels x 32 depths.
// Wave w owns depths 8w..8w+7. Owner lane (pl, j) holds bilinear setup for
// depth j (j = lane&7).
// Feat: lane = (pl<3>, dp<1>, cg2<2>): 4 jp iters, each lane does depth
//       (dp*4+jp) x 8 channels via uint4 fp16 gathers; setup via shfl.
// Deps: lane = (pl<3>, ds<3>): own setup in regs, 8 ch = 1 uint4, no shfl.
// grid = HWN/8 = 2560 blocks.
// ---------------------------------------------------------------------------
__global__ __launch_bounds__(256) void cost_volume_k(
    const __half* __restrict__ featH,  // (V,HW,32) fp16
    const __half* __restrict__ depsH,  // (V,HW,8)  fp16
    const float* __restrict__ dvals,   // (D,HW)
    const float* __restrict__ regw,    // 40
    const float* __restrict__ pws,     // 24 (uniform -> scalar loads)
    float* __restrict__ out)
{
    __shared__ float cl [ND][9];
    __shared__ float dvl[ND][9];
    __shared__ float smax[8], sisum[8];

    const int t    = threadIdx.x;
    const int lane = t & 63;
    const int wid  = t >> 6;
    const int cg2  = lane & 3;          // feat channel group (8 ch each)
    const int dp   = (lane >> 2) & 1;   // feat depth-pair bit
    const int pl   = lane >> 3;
    const int pixg = blockIdx.x * 8 + pl;
    const int y    = pixg / WW;
    const int x    = pixg - y * WW;
    const float fx = (float)x, fy = (float)y;
    const int dbase = wid * 8;
    const int plbase = lane & 0x38;

    float RX[2], RY[2], RZ[2], T0[2], T1[2], T2[2];
    #pragma unroll
    for (int v = 0; v < 2; v++) {
        const float* q = pws + v*12;
        RX[v] = q[0]*fx + q[1]*fy + q[2];
        RY[v] = q[3]*fx + q[4]*fy + q[5];
        RZ[v] = q[6]*fx + q[7]*fy + q[8];
        T0[v] = q[9]; T1[v] = q[10]; T2[v] = q[11];
    }

    // Owner lane (pl, j=lane&7) computes bilinear setup for depth dbase+j.
    int SW00[2], SW10[2], SW01[2], SW11[2];   // broadcast half2 weights
    int SO00[2], SO10[2], SO01[2], SO11[2];   // element offsets * NCF
    {
        float dvv_own = dvals[(dbase + (lane & 7))*HWN + pixg];
        dvl[dbase + (lane & 7)][pl] = dvv_own;
        #pragma unroll
        for (int v = 0; v < 2; v++) {
            float pz = RZ[v]*dvv_own + T2[v];
            float iz = __builtin_amdgcn_rcpf(pz);
            float px = (RX[v]*dvv_own + T0[v]) * iz;
            float py = (RY[v]*dvv_own + T1[v]) * iz;
            float x0f = floorf(px), y0f = floorf(py);
            int x0 = (int)x0f, y0 = (int)y0f;
            float wx = px - x0f, wy = py - y0f;
            float omx = 1.f - wx, omy = 1.f - wy;
            bool vx0 = (x0 >= 0) & (x0 < WW);
            bool vx1 = (x0+1 >= 0) & (x0+1 < WW);
            bool vy0 = (y0 >= 0) & (y0 < HH);
            bool vy1 = (y0+1 >= 0) & (y0+1 < HH);
            float W00 = (vx0 && vy0) ? omx*omy : 0.f;
            float W10 = (vx1 && vy0) ? wx*omy  : 0.f;
            float W01 = (vx0 && vy1) ? omx*wy  : 0.f;
            float W11 = (vx1 && vy1) ? wx*wy   : 0.f;
            __half2 h;
            h = __float2half2_rn(W00); SW00[v] = *(int*)&h;
            h = __float2half2_rn(W10); SW10[v] = *(int*)&h;
            h = __float2half2_rn(W01); SW01[v] = *(int*)&h;
            h = __float2half2_rn(W11); SW11[v] = *(int*)&h;
            int xc0 = min(max(x0,   0), WW-1);
            int xc1 = min(max(x0+1, 0), WW-1);
            int yc0 = min(max(y0,   0), HH-1);
            int yc1 = min(max(y0+1, 0), HH-1);
            SO00[v] = (yc0*WW + xc0)*NCF;
            SO10[v] = (yc0*WW + xc1)*NCF;
            SO01[v] = (yc1*WW + xc0)*NCF;
            SO11[v] = (yc1*WW + xc1)*NCF;
        }
    }

    #define H2OF(u, k) (((const __half2*)&(u))[k])
    // 8-channel bilinear accumulate from 4 uint4 corners
    #define INTERP8(u00, u10, u01, u11, W00p, W10p, W01p, W11p)                \
        { _Pragma("unroll")                                                    \
          for (int k = 0; k < 4; k++) {                                        \
            __half2 wv = __hmul2(H2OF(u00,k), W00p);                           \
            wv = __hfma2(H2OF(u10,k), W10p, wv);                               \
            wv = __hfma2(H2OF(u01,k), W01p, wv);                               \
            wv = __hfma2(H2OF(u11,k), W11p, wv);                               \
            float2 f = __half22float2(wv);                                     \
            s[2*k]   += f.x; q[2*k]   = fmaf(f.x, f.x, q[2*k]);                \
            s[2*k+1] += f.y; q[2*k+1] = fmaf(f.y, f.y, q[2*k+1]);              \
          } }

    // ================== FEAT PHASE ==================
    {
        uint4 ur = *(const uint4*)(featH + (size_t)pixg*NCF + cg2*8);
        float rx[8];
        {
            float2 f;
            f = __half22float2(H2OF(ur,0)); rx[0]=f.x; rx[1]=f.y;
            f = __half22float2(H2OF(ur,1)); rx[2]=f.x; rx[3]=f.y;
            f = __half22float2(H2OF(ur,2)); rx[4]=f.x; rx[5]=f.y;
            f = __half22float2(H2OF(ur,3)); rx[6]=f.x; rx[7]=f.y;
        }
        float wca[8], wcb[8];
        {
            float4 wa = *(const float4*)(regw + cg2*8);
            float4 wb = *(const float4*)(regw + cg2*8 + 4);
            wca[0]=wa.x*(1.f/3.f); wca[1]=wa.y*(1.f/3.f); wca[2]=wa.z*(1.f/3.f); wca[3]=wa.w*(1.f/3.f);
            wca[4]=wb.x*(1.f/3.f); wca[5]=wb.y*(1.f/3.f); wca[6]=wb.z*(1.f/3.f); wca[7]=wb.w*(1.f/3.f);
            wcb[0]=wa.x*(1.f/9.f); wcb[1]=wa.y*(1.f/9.f); wcb[2]=wa.z*(1.f/9.f); wcb[3]=wa.w*(1.f/9.f);
            wcb[4]=wb.x*(1.f/9.f); wcb[5]=wb.y*(1.f/9.f); wcb[6]=wb.z*(1.f/9.f); wcb[7]=wb.w*(1.f/9.f);
        }
        const __half* b1 = featH + (size_t)1*HWN*NCF + cg2*8;
        const __half* b2 = featH + (size_t)2*HWN*NCF + cg2*8;

        #pragma unroll 2
        for (int jp = 0; jp < 4; jp++) {
            const int jj  = (dp << 2) | jp;
            const int src = plbase | jj;
            float s[8], q[8];
            #pragma unroll
            for (int i = 0; i < 8; i++) { s[i] = rx[i]; q[i] = rx[i]*rx[i]; }

            #pragma unroll
            for (int v = 0; v < 2; v++) {
                int w00i = __shfl(SW00[v], src, 64);
                int w10i = __shfl(SW10[v], src, 64);
                int w01i = __shfl(SW01[v], src, 64);
                int w11i = __shfl(SW11[v], src, 64);
                int o00  = __shfl(SO00[v], src, 64);
                int o10  = __shfl(SO10[v], src, 64);
                int o01  = __shfl(SO01[v], src, 64);
                int o11  = __shfl(SO11[v], src, 64);
                __half2 W00p = *(__half2*)&w00i, W10p = *(__half2*)&w10i;
                __half2 W01p = *(__half2*)&w01i, W11p = *(__half2*)&w11i;
                const __half* b = v ? b2 : b1;
                uint4 u00 = *(const uint4*)(b + o00);
                uint4 u10 = *(const uint4*)(b + o10);
                uint4 u01 = *(const uint4*)(b + o01);
                uint4 u11 = *(const uint4*)(b + o11);
                INTERP8(u00, u10, u01, u11, W00p, W10p, W01p, W11p)
            }
            float part = wca[0]*q[0] - wcb[0]*s[0]*s[0];
            #pragma unroll
            for (int i = 1; i < 8; i++) {
                part = fmaf(wca[i], q[i], part);
                part = fmaf(-wcb[i], s[i]*s[i], part);
            }
            part += __shfl_xor(part, 1);
            part += __shfl_xor(part, 2);
            if (cg2 == 0) cl[dbase + jj][pl] = part;
        }
    }

    // ================== DEPS PHASE ==================
    // lane = (pl<3>, ds<3>): setup for depth ds already in this lane's regs.
    {
        const int d = dbase + (lane & 7);
        uint4 ur = *(const uint4*)(depsH + (size_t)pixg*NCD);
        float rx[8];
        {
            float2 f;
            f = __half22float2(H2OF(ur,0)); rx[0]=f.x; rx[1]=f.y;
            f = __half22float2(H2OF(ur,1)); rx[2]=f.x; rx[3]=f.y;
            f = __half22float2(H2OF(ur,2)); rx[4]=f.x; rx[5]=f.y;
            f = __half22float2(H2OF(ur,3)); rx[6]=f.x; rx[7]=f.y;
        }
        float wca[8], wcb[8];
        {
            float4 wa = *(const float4*)(regw + NCF);
            float4 wb = *(const float4*)(regw + NCF + 4);
            wca[0]=wa.x*(1.f/3.f); wca[1]=wa.y*(1.f/3.f); wca[2]=wa.z*(1.f/3.f); wca[3]=wa.w*(1.f/3.f);
            wca[4]=wb.x*(1.f/3.f); wca[5]=wb.y*(1.f/3.f); wca[6]=wb.z*(1.f/3.f); wca[7]=wb.w*(1.f/3.f);
            wcb[0]=wa.x*(1.f/9.f); wcb[1]=wa.y*(1.f/9.f); wcb[2]=wa.z*(1.f/9.f); wcb[3]=wa.w*(1.f/9.f);
            wcb[4]=wb.x*(1.f/9.f); wcb[5]=wb.y*(1.f/9.f); wcb[6]=wb.z*(1.f/9.f); wcb[7]=wb.w*(1.f/9.f);
        }
        float s[8], q[8];
        #pragma unroll
        for (int i = 0; i < 8; i++) { s[i] = rx[i]; q[i] = rx[i]*rx[i]; }

        #pragma unroll
        for (int v = 0; v < 2; v++) {
            int o00 = SO00[v] >> 2;
            int o10 = SO10[v] >> 2;
            int o01 = SO01[v] >> 2;
            int o11 = SO11[v] >> 2;
            __half2 W00p = *(__half2*)&SW00[v], W10p = *(__half2*)&SW10[v];
            __half2 W01p = *(__half2*)&SW01[v], W11p = *(__half2*)&SW11[v];
            const __half* b = depsH + (size_t)(v+1)*HWN*NCD;
            uint4 u00 = *(const uint4*)(b + o00);
            uint4 u10 = *(const uint4*)(b + o10);
            uint4 u01 = *(const uint4*)(b + o01);
            uint4 u11 = *(const uint4*)(b + o11);
            INTERP8(u00, u10, u01, u11, W00p, W10p, W01p, W11p)
        }
        float part = wca[0]*q[0] - wcb[0]*s[0]*s[0];
        #pragma unroll
        for (int i = 1; i < 8; i++) {
            part = fmaf(wca[i], q[i], part);
            part = fmaf(-wcb[i], s[i]*s[i], part);
        }
        cl[d][pl] += part;   // unique (d, pl) per lane; same-wave ordering OK
    }
    __syncthreads();

    // ================== SOFTMAX + MOMENTS ==================
    if (t < 8) {
        const int plx  = t;
        const int pixo = blockIdx.x * 8 + plx;
        float m = -1e30f;
        #pragma unroll
        for (int d = 0; d < ND; d++) m = fmaxf(m, cl[d][plx]);
        float sum = 0.f, pd = 0.f, pd2 = 0.f;
        #pragma unroll
        for (int d = 0; d < ND; d++) {
            float e   = __expf(cl[d][plx] - m);
            float dvv = dvl[d][plx];
            sum += e;
            pd  = fmaf(e, dvv, pd);
            pd2 = fmaf(e, dvv*dvv, pd2);
        }
        float isum  = 1.f / sum;
        float depth = pd * isum;
        float sv    = pd2 * isum - depth*depth;
        float ev    = LAMBF * sqrtf(fmaxf(sv, 0.f));
        smax[plx]  = m;
        sisum[plx] = isum;
        out[pixo]       = depth;
        out[HWN + pixo] = ev;
    }
    __syncthreads();
    {
        const int plx  = t & 7;
        const int dd   = t >> 3;
        const int pixo = blockIdx.x * 8 + plx;
        out[2*HWN + dd*HWN + pixo] = __expf(cl[dd][plx] - smax[plx]) * sisum[plx];
    }
}

// ---------------------------------------------------------------------------
extern "C" void kernel_launch(void* const* d_in, const int* in_sizes, int n_in,
                              void* d_out, int out_size, void* d_ws, size_t ws_size,
                              hipStream_t stream) {
    const float* features = (const float*)d_in[0];   // (V,1,32,H,W)
    const float* deps     = (const float*)d_in[1];   // (V,1,8,H,W)
    const float* proj     = (const float*)d_in[2];   // (1,V,4,4)
    const float* dvals    = (const float*)d_in[3];   // (1,D,H,W)
    const float* regw     = (const float*)d_in[4];   // (1,40)

    float*  ws    = (float*)d_ws;
    float*  projw = ws;                              // 24 floats (64 reserved)
    __half* featH = (__half*)(ws + 64);              // 3*HW*32 halves
    __half* depsH = featH + (size_t)NV*HWN*NCF;      // 3*HW*8 halves

    dim3 tg(WW/32, HH, 2*NV);
    prep_k<<<tg, 256, 0, stream>>>(features, deps, proj, featH, depsH, projw);

    cost_volume_k<<<HWN/8, 256, 0, stream>>>(featH, depsH, dvals, regw, projw,
                                             (float*)d_out);
}

// Round 11
// 91.809 us; speedup vs baseline: 1.1737x; 1.0272x over previous
//
#include <hip/hip_runtime.h>
#include <hip/hip_fp16.h>
#include <math.h>

#define HH   128
#define WW   160
#define HWN  (HH*WW)      // 20480
#define NCF  32           // feature channels
#define NCD  8            // deps channels
#define ND   32           // depths
#define NV   3            // views
#define LAMBF 1.5f

// ---------------------------------------------------------------------------
// Prep: transpose (V,CH,H,W) f32 -> (V,HW,CH) fp16 channel-last.
// block(0,0,0)/thread0 also computes proj_v @ inv(proj_ref) -> projw[24].
// ---------------------------------------------------------------------------
template <int CH>
__device__ void transpose_tile(const float* __restrict__ src, __half* __restrict__ dst,
                               float (*lds)[33], int tid) {
    for (int i = tid; i < CH*8; i += 256) {
        int c = i >> 3, xg = (i & 7) << 2;
        *(float4*)&lds[c][xg] = *(const float4*)(src + c*HWN + xg);
    }
    __syncthreads();
    for (int i = tid; i < 32*(CH/4); i += 256) {
        int xl = i / (CH/4), c4 = (i % (CH/4)) * 4;
        __half2 h0 = __floats2half2_rn(lds[c4][xl],   lds[c4+1][xl]);
        __half2 h1 = __floats2half2_rn(lds[c4+2][xl], lds[c4+3][xl]);
        uint2 u; u.x = *(unsigned*)&h0; u.y = *(unsigned*)&h1;
        *(uint2*)(dst + xl*CH + c4) = u;
    }
}

__global__ __launch_bounds__(256) void prep_k(const float* __restrict__ feat,
                                              const float* __restrict__ deps,
                                              const float* __restrict__ proj,
                                              __half* __restrict__ featH,
                                              __half* __restrict__ depsH,
                                              float* __restrict__ projw) {
    if (blockIdx.x == 0 && blockIdx.y == 0 && blockIdx.z == 0 && threadIdx.x == 0) {
        float M00 = proj[0], M01 = proj[1], M02 = proj[2],  m0 = proj[3];
        float M10 = proj[4], M11 = proj[5], M12 = proj[6],  m1 = proj[7];
        float M20 = proj[8], M21 = proj[9], M22 = proj[10], m2 = proj[11];
        float c00 =  (M11*M22 - M12*M21);
        float c01 = -(M10*M22 - M12*M20);
        float c02 =  (M10*M21 - M11*M20);
        float det = M00*c00 + M01*c01 + M02*c02;
        float id  = 1.f / det;
        float i00 = c00*id, i01 = -(M01*M22 - M02*M21)*id, i02 =  (M01*M12 - M02*M11)*id;
        float i10 = c01*id, i11 =  (M00*M22 - M02*M20)*id, i12 = -(M00*M12 - M02*M10)*id;
        float i20 = c02*id, i21 = -(M00*M21 - M01*M20)*id, i22 =  (M00*M11 - M01*M10)*id;
        float t0 = -(i00*m0 + i01*m1 + i02*m2);
        float t1 = -(i10*m0 + i11*m1 + i12*m2);
        float t2 = -(i20*m0 + i21*m1 + i22*m2);
        #pragma unroll
        for (int v = 1; v < NV; v++) {
            const float* S = proj + v*16;
            float s00 = S[0], s01 = S[1], s02 = S[2],  st0 = S[3];
            float s10 = S[4], s11 = S[5], s12 = S[6],  st1 = S[7];
            float s20 = S[8], s21 = S[9], s22 = S[10], st2 = S[11];
            float* o = projw + (v-1)*12;
            o[0] = s00*i00 + s01*i10 + s02*i20;
            o[1] = s00*i01 + s01*i11 + s02*i21;
            o[2] = s00*i02 + s01*i12 + s02*i22;
            o[3] = s10*i00 + s11*i10 + s12*i20;
            o[4] = s10*i01 + s11*i11 + s12*i21;
            o[5] = s10*i02 + s11*i12 + s12*i22;
            o[6] = s20*i00 + s21*i10 + s22*i20;
            o[7] = s20*i01 + s21*i11 + s22*i21;
            o[8] = s20*i02 + s21*i12 + s22*i22;
            o[9]  = s00*t0 + s01*t1 + s02*t2 + st0;
            o[10] = s10*t0 + s11*t1 + s12*t2 + st1;
            o[11] = s20*t0 + s21*t1 + s22*t2 + st2;
        }
    }

    __shared__ float lds[NCF][33];
    const int z  = blockIdx.z;
    const int xb = blockIdx.x * 32;
    const int y  = blockIdx.y;
    if (z < NV) {
        transpose_tile<NCF>(feat + (size_t)(z*NCF)*HWN + y*WW + xb,
                            featH + (size_t)(z*HWN + y*WW + xb) * NCF,
                            lds, threadIdx.x);
    } else {
        transpose_tile<NCD>(deps + (size_t)((z - NV)*NCD)*HWN + y*WW + xb,
                            depsH + (size_t)((z - NV)*HWN + y*WW + xb) * NCD,
                            lds, threadIdx.x);
    }
}

// ---------------------------------------------------------------------------
// Main: block = 256 threads = 4 waves = 8 pixels x 32 depths.
// Wave w owns depths 8w..8w+7. Owner lane (pl, j=lane&7) holds bilinear
// setup for depth dbase+j.
// Feat: lane = (pl<3>, dp<1>, cg2<2>): 4 jp iters, 8ch uint4 gathers, setup
//       via shfl; variance accumulated fully in half2.
// Deps: lane = (pl<3>, ds<3>): own setup in regs, 8 ch = 1 uint4, no shfl.
// grid = HWN/8 = 2560 blocks.
// ---------------------------------------------------------------------------
__global__ __launch_bounds__(256) void cost_volume_k(
    const __half* __restrict__ featH,  // (V,HW,32) fp16
    const __half* __restrict__ depsH,  // (V,HW,8)  fp16
    const float* __restrict__ dvals,   // (D,HW)
    const float* __restrict__ regw,    // 40
    const float* __restrict__ pws,     // 24 (uniform -> scalar loads)
    float* __restrict__ out)
{
    __shared__ float cl [ND][9];
    __shared__ float dvl[ND][9];
    __shared__ float smax[8], sisum[8];

    const int t    = threadIdx.x;
    const int lane = t & 63;
    const int wid  = t >> 6;
    const int cg2  = lane & 3;          // feat channel group (8 ch each)
    const int dp   = (lane >> 2) & 1;   // feat depth-pair bit
    const int pl   = lane >> 3;
    const int pixg = blockIdx.x * 8 + pl;
    const int y    = pixg / WW;
    const int x    = pixg - y * WW;
    const float fx = (float)x, fy = (float)y;
    const int dbase = wid * 8;
    const int plbase = lane & 0x38;

    float RX[2], RY[2], RZ[2], T0[2], T1[2], T2[2];
    #pragma unroll
    for (int v = 0; v < 2; v++) {
        const float* q = pws + v*12;
        RX[v] = q[0]*fx + q[1]*fy + q[2];
        RY[v] = q[3]*fx + q[4]*fy + q[5];
        RZ[v] = q[6]*fx + q[7]*fy + q[8];
        T0[v] = q[9]; T1[v] = q[10]; T2[v] = q[11];
    }

    // Owner lane (pl, j=lane&7) computes bilinear setup for depth dbase+j.
    int SW00[2], SW10[2], SW01[2], SW11[2];   // broadcast half2 weights
    int SO00[2], SO10[2], SO01[2], SO11[2];   // element offsets * NCF
    {
        float dvv_own = dvals[(dbase + (lane & 7))*HWN + pixg];
        dvl[dbase + (lane & 7)][pl] = dvv_own;
        #pragma unroll
        for (int v = 0; v < 2; v++) {
            float pz = RZ[v]*dvv_own + T2[v];
            float iz = __builtin_amdgcn_rcpf(pz);
            float px = (RX[v]*dvv_own + T0[v]) * iz;
            float py = (RY[v]*dvv_own + T1[v]) * iz;
            float x0f = floorf(px), y0f = floorf(py);
            int x0 = (int)x0f, y0 = (int)y0f;
            float wx = px - x0f, wy = py - y0f;
            float omx = 1.f - wx, omy = 1.f - wy;
            bool vx0 = (x0 >= 0) & (x0 < WW);
            bool vx1 = (x0+1 >= 0) & (x0+1 < WW);
            bool vy0 = (y0 >= 0) & (y0 < HH);
            bool vy1 = (y0+1 >= 0) & (y0+1 < HH);
            float W00 = (vx0 && vy0) ? omx*omy : 0.f;
            float W10 = (vx1 && vy0) ? wx*omy  : 0.f;
            float W01 = (vx0 && vy1) ? omx*wy  : 0.f;
            float W11 = (vx1 && vy1) ? wx*wy   : 0.f;
            __half2 h;
            h = __float2half2_rn(W00); SW00[v] = *(int*)&h;
            h = __float2half2_rn(W10); SW10[v] = *(int*)&h;
            h = __float2half2_rn(W01); SW01[v] = *(int*)&h;
            h = __float2half2_rn(W11); SW11[v] = *(int*)&h;
            int xc0 = min(max(x0,   0), WW-1);
            int xc1 = min(max(x0+1, 0), WW-1);
            int yc0 = min(max(y0,   0), HH-1);
            int yc1 = min(max(y0+1, 0), HH-1);
            SO00[v] = (yc0*WW + xc0)*NCF;
            SO10[v] = (yc0*WW + xc1)*NCF;
            SO01[v] = (yc1*WW + xc0)*NCF;
            SO11[v] = (yc1*WW + xc1)*NCF;
        }
    }

    #define H2OF(u, k) (((const __half2*)&(u))[k])
    // 8-channel bilinear + variance accumulate, all in half2
    #define INTERP8H(u00, u10, u01, u11, W00p, W10p, W01p, W11p)               \
        { _Pragma("unroll")                                                    \
          for (int k = 0; k < 4; k++) {                                        \
            __half2 wv = __hmul2(H2OF(u00,k), W00p);                           \
            wv = __hfma2(H2OF(u10,k), W10p, wv);                               \
            wv = __hfma2(H2OF(u01,k), W01p, wv);                               \
            wv = __hfma2(H2OF(u11,k), W11p, wv);                               \
            s2[k] = __hadd2(s2[k], wv);                                        \
            q2[k] = __hfma2(wv, wv, q2[k]);                                    \
          } }

    // ================== FEAT PHASE ==================
    {
        const uint4 ur4 = *(const uint4*)(featH + (size_t)pixg*NCF + cg2*8);
        __half2 wca2[4], nwcb2[4];
        {
            float4 wa = *(const float4*)(regw + cg2*8);
            float4 wb = *(const float4*)(regw + cg2*8 + 4);
            wca2[0]  = __floats2half2_rn( wa.x*(1.f/3.f),  wa.y*(1.f/3.f));
            wca2[1]  = __floats2half2_rn( wa.z*(1.f/3.f),  wa.w*(1.f/3.f));
            wca2[2]  = __floats2half2_rn( wb.x*(1.f/3.f),  wb.y*(1.f/3.f));
            wca2[3]  = __floats2half2_rn( wb.z*(1.f/3.f),  wb.w*(1.f/3.f));
            nwcb2[0] = __floats2half2_rn(-wa.x*(1.f/9.f), -wa.y*(1.f/9.f));
            nwcb2[1] = __floats2half2_rn(-wa.z*(1.f/9.f), -wa.w*(1.f/9.f));
            nwcb2[2] = __floats2half2_rn(-wb.x*(1.f/9.f), -wb.y*(1.f/9.f));
            nwcb2[3] = __floats2half2_rn(-wb.z*(1.f/9.f), -wb.w*(1.f/9.f));
        }
        const __half* b1 = featH + (size_t)1*HWN*NCF + cg2*8;
        const __half* b2 = featH + (size_t)2*HWN*NCF + cg2*8;

        #pragma unroll 2
        for (int jp = 0; jp < 4; jp++) {
            const int jj  = (dp << 2) | jp;
            const int src = plbase | jj;

            // broadcast both views' setup first (DS pipe), then all 8 loads
            int wA00 = __shfl(SW00[0], src, 64), wA10 = __shfl(SW10[0], src, 64);
            int wA01 = __shfl(SW01[0], src, 64), wA11 = __shfl(SW11[0], src, 64);
            int oA00 = __shfl(SO00[0], src, 64), oA10 = __shfl(SO10[0], src, 64);
            int oA01 = __shfl(SO01[0], src, 64), oA11 = __shfl(SO11[0], src, 64);
            int wB00 = __shfl(SW00[1], src, 64), wB10 = __shfl(SW10[1], src, 64);
            int wB01 = __shfl(SW01[1], src, 64), wB11 = __shfl(SW11[1], src, 64);
            int oB00 = __shfl(SO00[1], src, 64), oB10 = __shfl(SO10[1], src, 64);
            int oB01 = __shfl(SO01[1], src, 64), oB11 = __shfl(SO11[1], src, 64);

            uint4 a00 = *(const uint4*)(b1 + oA00);
            uint4 a10 = *(const uint4*)(b1 + oA10);
            uint4 a01 = *(const uint4*)(b1 + oA01);
            uint4 a11 = *(const uint4*)(b1 + oA11);
            uint4 c00 = *(const uint4*)(b2 + oB00);
            uint4 c10 = *(const uint4*)(b2 + oB10);
            uint4 c01 = *(const uint4*)(b2 + oB01);
            uint4 c11 = *(const uint4*)(b2 + oB11);

            __half2 s2[4], q2[4];
            #pragma unroll
            for (int k = 0; k < 4; k++) {
                __half2 r = H2OF(ur4, k);
                s2[k] = r;
                q2[k] = __hmul2(r, r);
            }
            INTERP8H(a00, a10, a01, a11,
                     *(__half2*)&wA00, *(__half2*)&wA10,
                     *(__half2*)&wA01, *(__half2*)&wA11)
            INTERP8H(c00, c10, c01, c11,
                     *(__half2*)&wB00, *(__half2*)&wB10,
                     *(__half2*)&wB01, *(__half2*)&wB11)

            __half2 acc = __hmul2(q2[0], wca2[0]);
            acc = __hfma2(__hmul2(s2[0], s2[0]), nwcb2[0], acc);
            #pragma unroll
            for (int k = 1; k < 4; k++) {
                acc = __hfma2(q2[k], wca2[k], acc);
                acc = __hfma2(__hmul2(s2[k], s2[k]), nwcb2[k], acc);
            }
            float2 af = __half22float2(acc);
            float part = af.x + af.y;
            part += __shfl_xor(part, 1);
            part += __shfl_xor(part, 2);
            if (cg2 == 0) cl[dbase + jj][pl] = part;
        }
    }

    // ================== DEPS PHASE ==================
    // lane = (pl<3>, ds<3>): setup for depth ds already in this lane's regs.
    {
        const int d = dbase + (lane & 7);
        const uint4 ur4 = *(const uint4*)(depsH + (size_t)pixg*NCD);
        __half2 wca2[4], nwcb2[4];
        {
            float4 wa = *(const float4*)(regw + NCF);
            float4 wb = *(const float4*)(regw + NCF + 4);
            wca2[0]  = __floats2half2_rn( wa.x*(1.f/3.f),  wa.y*(1.f/3.f));
            wca2[1]  = __floats2half2_rn( wa.z*(1.f/3.f),  wa.w*(1.f/3.f));
            wca2[2]  = __floats2half2_rn( wb.x*(1.f/3.f),  wb.y*(1.f/3.f));
            wca2[3]  = __floats2half2_rn( wb.z*(1.f/3.f),  wb.w*(1.f/3.f));
            nwcb2[0] = __floats2half2_rn(-wa.x*(1.f/9.f), -wa.y*(1.f/9.f));
            nwcb2[1] = __floats2half2_rn(-wa.z*(1.f/9.f), -wa.w*(1.f/9.f));
            nwcb2[2] = __floats2half2_rn(-wb.x*(1.f/9.f), -wb.y*(1.f/9.f));
            nwcb2[3] = __floats2half2_rn(-wb.z*(1.f/9.f), -wb.w*(1.f/9.f));
        }
        const __half* d1 = depsH + (size_t)1*HWN*NCD;
        const __half* d2 = depsH + (size_t)2*HWN*NCD;
        int oA00 = SO00[0] >> 2, oA10 = SO10[0] >> 2,
            oA01 = SO01[0] >> 2, oA11 = SO11[0] >> 2;
        int oB00 = SO00[1] >> 2, oB10 = SO10[1] >> 2,
            oB01 = SO01[1] >> 2, oB11 = SO11[1] >> 2;

        uint4 a00 = *(const uint4*)(d1 + oA00);
        uint4 a10 = *(const uint4*)(d1 + oA10);
        uint4 a01 = *(const uint4*)(d1 + oA01);
        uint4 a11 = *(const uint4*)(d1 + oA11);
        uint4 c00 = *(const uint4*)(d2 + oB00);
        uint4 c10 = *(const uint4*)(d2 + oB10);
        uint4 c01 = *(const uint4*)(d2 + oB01);
        uint4 c11 = *(const uint4*)(d2 + oB11);

        __half2 s2[4], q2[4];
        #pragma unroll
        for (int k = 0; k < 4; k++) {
            __half2 r = H2OF(ur4, k);
            s2[k] = r;
            q2[k] = __hmul2(r, r);
        }
        INTERP8H(a00, a10, a01, a11,
                 *(__half2*)&SW00[0], *(__half2*)&SW10[0],
                 *(__half2*)&SW01[0], *(__half2*)&SW11[0])
        INTERP8H(c00, c10, c01, c11,
                 *(__half2*)&SW00[1], *(__half2*)&SW10[1],
                 *(__half2*)&SW01[1], *(__half2*)&SW11[1])

        __half2 acc = __hmul2(q2[0], wca2[0]);
        acc = __hfma2(__hmul2(s2[0], s2[0]), nwcb2[0], acc);
        #pragma unroll
        for (int k = 1; k < 4; k++) {
            acc = __hfma2(q2[k], wca2[k], acc);
            acc = __hfma2(__hmul2(s2[k], s2[k]), nwcb2[k], acc);
        }
        float2 af = __half22float2(acc);
        cl[d][pl] += af.x + af.y;   // unique (d,pl) per lane
    }
    __syncthreads();

    // ================== SOFTMAX + MOMENTS ==================
    if (t < 8) {
        const int plx  = t;
        const int pixo = blockIdx.x * 8 + plx;
        float m = -1e30f;
        #pragma unroll
        for (int d = 0; d < ND; d++) m = fmaxf(m, cl[d][plx]);
        float sum = 0.f, pd = 0.f, pd2 = 0.f;
        #pragma unroll
        for (int d = 0; d < ND; d++) {
            float e   = __expf(cl[d][plx] - m);
            float dvv = dvl[d][plx];
            sum += e;
            pd  = fmaf(e, dvv, pd);
            pd2 = fmaf(e, dvv*dvv, pd2);
        }
        float isum  = 1.f / sum;
        float depth = pd * isum;
        float sv    = pd2 * isum - depth*depth;
        float ev    = LAMBF * sqrtf(fmaxf(sv, 0.f));
        smax[plx]  = m;
        sisum[plx] = isum;
        out[pixo]       = depth;
        out[HWN + pixo] = ev;
    }
    __syncthreads();
    {
        const int plx  = t & 7;
        const int dd   = t >> 3;
        const int pixo = blockIdx.x * 8 + plx;
        out[2*HWN + dd*HWN + pixo] = __expf(cl[dd][plx] - smax[plx]) * sisum[plx];
    }
}

// ---------------------------------------------------------------------------
extern "C" void kernel_launch(void* const* d_in, const int* in_sizes, int n_in,
                              void* d_out, int out_size, void* d_ws, size_t ws_size,
                              hipStream_t stream) {
    const float* features = (const float*)d_in[0];   // (V,1,32,H,W)
    const float* deps     = (const float*)d_in[1];   // (V,1,8,H,W)
    const float* proj     = (const float*)d_in[2];   // (1,V,4,4)
    const float* dvals    = (const float*)d_in[3];   // (1,D,H,W)
    const float* regw     = (const float*)d_in[4];   // (1,40)

    float*  ws    = (float*)d_ws;
    float*  projw = ws;                              // 24 floats (64 reserved)
    __half* featH = (__half*)(ws + 64);              // 3*HW*32 halves
    __half* depsH = featH + (size_t)NV*HWN*NCF;      // 3*HW*8 halves

    dim3 tg(WW/32, HH, 2*NV);
    prep_k<<<tg, 256, 0, stream>>>(features, deps, proj, featH, depsH, projw);

    cost_volume_k<<<HWN/8, 256, 0, stream>>>(featH, depsH, dvals, regw, projw,
                                             (float*)d_out);
}

// Round 12
// 91.267 us; speedup vs baseline: 1.1806x; 1.0059x over previous
//
#include <hip/hip_runtime.h>
#include <hip/hip_fp16.h>
#include <math.h>

#define HH   128
#define WW   160
#define HWN  (HH*WW)      // 20480
#define NCF  32           // feature channels
#define NCD  8            // deps channels
#define ND   32           // depths
#define NV   3            // views
#define LAMBF 1.5f

// ---------------------------------------------------------------------------
// Prep: transpose (V,CH,H,W) f32 -> (V,HW,CH) fp16 channel-last.
// block(0,0,0)/thread0 also computes proj_v @ inv(proj_ref) -> projw[24].
// ---------------------------------------------------------------------------
template <int CH>
__device__ void transpose_tile(const float* __restrict__ src, __half* __restrict__ dst,
                               float (*lds)[33], int tid) {
    for (int i = tid; i < CH*8; i += 256) {
        int c = i >> 3, xg = (i & 7) << 2;
        *(float4*)&lds[c][xg] = *(const float4*)(src + c*HWN + xg);
    }
    __syncthreads();
    for (int i = tid; i < 32*(CH/4); i += 256) {
        int xl = i / (CH/4), c4 = (i % (CH/4)) * 4;
        __half2 h0 = __floats2half2_rn(lds[c4][xl],   lds[c4+1][xl]);
        __half2 h1 = __floats2half2_rn(lds[c4+2][xl], lds[c4+3][xl]);
        uint2 u; u.x = *(unsigned*)&h0; u.y = *(unsigned*)&h1;
        *(uint2*)(dst + xl*CH + c4) = u;
    }
}

__global__ __launch_bounds__(256) void prep_k(const float* __restrict__ feat,
                                              const float* __restrict__ deps,
                                              const float* __restrict__ proj,
                                              __half* __restrict__ featH,
                                              __half* __restrict__ depsH,
                                              float* __restrict__ projw) {
    if (blockIdx.x == 0 && blockIdx.y == 0 && blockIdx.z == 0 && threadIdx.x == 0) {
        float M00 = proj[0], M01 = proj[1], M02 = proj[2],  m0 = proj[3];
        float M10 = proj[4], M11 = proj[5], M12 = proj[6],  m1 = proj[7];
        float M20 = proj[8], M21 = proj[9], M22 = proj[10], m2 = proj[11];
        float c00 =  (M11*M22 - M12*M21);
        float c01 = -(M10*M22 - M12*M20);
        float c02 =  (M10*M21 - M11*M20);
        float det = M00*c00 + M01*c01 + M02*c02;
        float id  = 1.f / det;
        float i00 = c00*id, i01 = -(M01*M22 - M02*M21)*id, i02 =  (M01*M12 - M02*M11)*id;
        float i10 = c01*id, i11 =  (M00*M22 - M02*M20)*id, i12 = -(M00*M12 - M02*M10)*id;
        float i20 = c02*id, i21 = -(M00*M21 - M01*M20)*id, i22 =  (M00*M11 - M01*M10)*id;
        float t0 = -(i00*m0 + i01*m1 + i02*m2);
        float t1 = -(i10*m0 + i11*m1 + i12*m2);
        float t2 = -(i20*m0 + i21*m1 + i22*m2);
        #pragma unroll
        for (int v = 1; v < NV; v++) {
            const float* S = proj + v*16;
            float s00 = S[0], s01 = S[1], s02 = S[2],  st0 = S[3];
            float s10 = S[4], s11 = S[5], s12 = S[6],  st1 = S[7];
            float s20 = S[8], s21 = S[9], s22 = S[10], st2 = S[11];
            float* o = projw + (v-1)*12;
            o[0] = s00*i00 + s01*i10 + s02*i20;
            o[1] = s00*i01 + s01*i11 + s02*i21;
            o[2] = s00*i02 + s01*i12 + s02*i22;
            o[3] = s10*i00 + s11*i10 + s12*i20;
            o[4] = s10*i01 + s11*i11 + s12*i21;
            o[5] = s10*i02 + s11*i12 + s12*i22;
            o[6] = s20*i00 + s21*i10 + s22*i20;
            o[7] = s20*i01 + s21*i11 + s22*i21;
            o[8] = s20*i02 + s21*i12 + s22*i22;
            o[9]  = s00*t0 + s01*t1 + s02*t2 + st0;
            o[10] = s10*t0 + s11*t1 + s12*t2 + st1;
            o[11] = s20*t0 + s21*t1 + s22*t2 + st2;
        }
    }

    __shared__ float lds[NCF][33];
    const int z  = blockIdx.z;
    const int xb = blockIdx.x * 32;
    const int y  = blockIdx.y;
    if (z < NV) {
        transpose_tile<NCF>(feat + (size_t)(z*NCF)*HWN + y*WW + xb,
                            featH + (size_t)(z*HWN + y*WW + xb) * NCF,
                            lds, threadIdx.x);
    } else {
        transpose_tile<NCD>(deps + (size_t)((z - NV)*NCD)*HWN + y*WW + xb,
                            depsH + (size_t)((z - NV)*HWN + y*WW + xb) * NCD,
                            lds, threadIdx.x);
    }
}

// ---------------------------------------------------------------------------
// Main: block = 256 threads = 4 waves = 8 pixels x 32 depths.
// Wave w owns depths 8w..8w+7. Owner lane (pl, j=lane&7) computes a CLAMPED
// 2x2 bilinear footprint for depth dbase+j: base offset (xb,yb) + 4 corner
// weights (border validity folded into the weights), packed into 2 half2
// ints + 1 offset -> 3 shfls/view in the feat loop. Row deltas are constant.
// Feat: lane = (pl<3>, dp<1>, cg2<2>), 4 iters, uint4 fp16 gathers, half2 math.
// Deps: lane = (pl<3>, ds<3>): own setup in regs, immediate-offset loads.
// grid = HWN/8 = 2560 blocks.
// ---------------------------------------------------------------------------
__global__ __launch_bounds__(256) void cost_volume_k(
    const __half* __restrict__ featH,  // (V,HW,32) fp16
    const __half* __restrict__ depsH,  // (V,HW,8)  fp16
    const float* __restrict__ dvals,   // (D,HW)
    const float* __restrict__ regw,    // 40
    const float* __restrict__ pws,     // 24 (uniform -> scalar loads)
    float* __restrict__ out)
{
    __shared__ float cl [ND][9];
    __shared__ float dvl[ND][9];
    __shared__ float smax[8], sisum[8];

    const int t    = threadIdx.x;
    const int lane = t & 63;
    const int wid  = t >> 6;
    const int cg2  = lane & 3;          // feat channel group (8 ch each)
    const int dp   = (lane >> 2) & 1;   // feat depth-pair bit
    const int pl   = lane >> 3;
    const int pixg = blockIdx.x * 8 + pl;
    const int y    = pixg / WW;
    const int x    = pixg - y * WW;
    const float fx = (float)x, fy = (float)y;
    const int dbase = wid * 8;
    const int plbase = lane & 0x38;

    float RX[2], RY[2], RZ[2], T0[2], T1[2], T2[2];
    #pragma unroll
    for (int v = 0; v < 2; v++) {
        const float* q = pws + v*12;
        RX[v] = q[0]*fx + q[1]*fy + q[2];
        RY[v] = q[3]*fx + q[4]*fy + q[5];
        RZ[v] = q[6]*fx + q[7]*fy + q[8];
        T0[v] = q[9]; T1[v] = q[10]; T2[v] = q[11];
    }

    // Owner lane (pl, j=lane&7): clamped-footprint setup for depth dbase+j.
    int SWA[2], SWB[2];   // packed half2: A=(W00,W10), B=(W01,W11)
    int SO [2];           // (yb*WW+xb)*NCF
    {
        float dvv_own = dvals[(dbase + (lane & 7))*HWN + pixg];
        dvl[dbase + (lane & 7)][pl] = dvv_own;
        #pragma unroll
        for (int v = 0; v < 2; v++) {
            float pz = RZ[v]*dvv_own + T2[v];
            float iz = __builtin_amdgcn_rcpf(pz);
            float px = (RX[v]*dvv_own + T0[v]) * iz;
            float py = (RY[v]*dvv_own + T1[v]) * iz;
            float x0f = floorf(px), y0f = floorf(py);
            int x0 = (int)x0f, y0 = (int)y0f;
            float wx = px - x0f, wy = py - y0f;
            float omx = 1.f - wx, omy = 1.f - wy;
            int xb = min(max(x0, 0), WW-2);
            int yb = min(max(y0, 0), HH-2);
            // pair weights on the clamped 2-sample footprint, zeroed if OOB
            float wx0 = (x0 == xb) ? omx : ((x0 == xb-1) ? wx  : 0.f);
            float wx1 = (x0 == xb) ? wx  : ((x0 == xb+1) ? omx : 0.f);
            float wy0 = (y0 == yb) ? omy : ((y0 == yb-1) ? wy  : 0.f);
            float wy1 = (y0 == yb) ? wy  : ((y0 == yb+1) ? omy : 0.f);
            __half2 hA = __floats2half2_rn(wx0*wy0, wx1*wy0);
            __half2 hB = __floats2half2_rn(wx0*wy1, wx1*wy1);
            SWA[v] = *(int*)&hA;
            SWB[v] = *(int*)&hB;
            SO[v]  = (yb*WW + xb)*NCF;
        }
    }

    #define H2OF(u, k) (((const __half2*)&(u))[k])
    // 8-channel bilinear + variance accumulate, all in half2
    #define INTERP8H(u00, u10, u01, u11, W00p, W10p, W01p, W11p)               \
        { _Pragma("unroll")                                                    \
          for (int k = 0; k < 4; k++) {                                        \
            __half2 wv = __hmul2(H2OF(u00,k), W00p);                           \
            wv = __hfma2(H2OF(u10,k), W10p, wv);                               \
            wv = __hfma2(H2OF(u01,k), W01p, wv);                               \
            wv = __hfma2(H2OF(u11,k), W11p, wv);                               \
            s2[k] = __hadd2(s2[k], wv);                                        \
            q2[k] = __hfma2(wv, wv, q2[k]);                                    \
          } }

    // ================== FEAT PHASE ==================
    {
        const uint4 ur4 = *(const uint4*)(featH + (size_t)pixg*NCF + cg2*8);
        __half2 wca2[4], nwcb2[4];
        {
            float4 wa = *(const float4*)(regw + cg2*8);
            float4 wb = *(const float4*)(regw + cg2*8 + 4);
            wca2[0]  = __floats2half2_rn( wa.x*(1.f/3.f),  wa.y*(1.f/3.f));
            wca2[1]  = __floats2half2_rn( wa.z*(1.f/3.f),  wa.w*(1.f/3.f));
            wca2[2]  = __floats2half2_rn( wb.x*(1.f/3.f),  wb.y*(1.f/3.f));
            wca2[3]  = __floats2half2_rn( wb.z*(1.f/3.f),  wb.w*(1.f/3.f));
            nwcb2[0] = __floats2half2_rn(-wa.x*(1.f/9.f), -wa.y*(1.f/9.f));
            nwcb2[1] = __floats2half2_rn(-wa.z*(1.f/9.f), -wa.w*(1.f/9.f));
            nwcb2[2] = __floats2half2_rn(-wb.x*(1.f/9.f), -wb.y*(1.f/9.f));
            nwcb2[3] = __floats2half2_rn(-wb.z*(1.f/9.f), -wb.w*(1.f/9.f));
        }
        const __half* b1 = featH + (size_t)1*HWN*NCF + cg2*8;
        const __half* b2 = featH + (size_t)2*HWN*NCF + cg2*8;

        #pragma unroll 2
        for (int jp = 0; jp < 4; jp++) {
            const int jj  = (dp << 2) | jp;
            const int src = plbase | jj;

            // 3 shfls per view: packed weights A,B + base offset
            int aA = __shfl(SWA[0], src, 64);
            int aB = __shfl(SWB[0], src, 64);
            int oA = __shfl(SO [0], src, 64);
            int bA = __shfl(SWA[1], src, 64);
            int bB = __shfl(SWB[1], src, 64);
            int oB = __shfl(SO [1], src, 64);

            const __half* pA0 = b1 + oA;
            const __half* pA1 = pA0 + WW*NCF;
            const __half* pB0 = b2 + oB;
            const __half* pB1 = pB0 + WW*NCF;
            uint4 a00 = *(const uint4*)(pA0);
            uint4 a10 = *(const uint4*)(pA0 + NCF);
            uint4 a01 = *(const uint4*)(pA1);
            uint4 a11 = *(const uint4*)(pA1 + NCF);
            uint4 c00 = *(const uint4*)(pB0);
            uint4 c10 = *(const uint4*)(pB0 + NCF);
            uint4 c01 = *(const uint4*)(pB1);
            uint4 c11 = *(const uint4*)(pB1 + NCF);

            __half2 s2[4], q2[4];
            #pragma unroll
            for (int k = 0; k < 4; k++) {
                __half2 r = H2OF(ur4, k);
                s2[k] = r;
                q2[k] = __hmul2(r, r);
            }
            {
                __half2 A = *(__half2*)&aA, B = *(__half2*)&aB;
                INTERP8H(a00, a10, a01, a11,
                         __low2half2(A), __high2half2(A),
                         __low2half2(B), __high2half2(B))
            }
            {
                __half2 A = *(__half2*)&bA, B = *(__half2*)&bB;
                INTERP8H(c00, c10, c01, c11,
                         __low2half2(A), __high2half2(A),
                         __low2half2(B), __high2half2(B))
            }

            __half2 acc = __hmul2(q2[0], wca2[0]);
            acc = __hfma2(__hmul2(s2[0], s2[0]), nwcb2[0], acc);
            #pragma unroll
            for (int k = 1; k < 4; k++) {
                acc = __hfma2(q2[k], wca2[k], acc);
                acc = __hfma2(__hmul2(s2[k], s2[k]), nwcb2[k], acc);
            }
            float2 af = __half22float2(acc);
            float part = af.x + af.y;
            part += __shfl_xor(part, 1);
            part += __shfl_xor(part, 2);
            if (cg2 == 0) cl[dbase + jj][pl] = part;
        }
    }

    // ================== DEPS PHASE ==================
    // lane = (pl<3>, ds<3>): setup in regs; all 4 corners immediate offsets.
    {
        const int d = dbase + (lane & 7);
        const uint4 ur4 = *(const uint4*)(depsH + (size_t)pixg*NCD);
        __half2 wca2[4], nwcb2[4];
        {
            float4 wa = *(const float4*)(regw + NCF);
            float4 wb = *(const float4*)(regw + NCF + 4);
            wca2[0]  = __floats2half2_rn( wa.x*(1.f/3.f),  wa.y*(1.f/3.f));
            wca2[1]  = __floats2half2_rn( wa.z*(1.f/3.f),  wa.w*(1.f/3.f));
            wca2[2]  = __floats2half2_rn( wb.x*(1.f/3.f),  wb.y*(1.f/3.f));
            wca2[3]  = __floats2half2_rn( wb.z*(1.f/3.f),  wb.w*(1.f/3.f));
            nwcb2[0] = __floats2half2_rn(-wa.x*(1.f/9.f), -wa.y*(1.f/9.f));
            nwcb2[1] = __floats2half2_rn(-wa.z*(1.f/9.f), -wa.w*(1.f/9.f));
            nwcb2[2] = __floats2half2_rn(-wb.x*(1.f/9.f), -wb.y*(1.f/9.f));
            nwcb2[3] = __floats2half2_rn(-wb.z*(1.f/9.f), -wb.w*(1.f/9.f));
        }
        const __half* pA0 = depsH + (size_t)1*HWN*NCD + (SO[0] >> 2);
        const __half* pB0 = depsH + (size_t)2*HWN*NCD + (SO[1] >> 2);

        uint4 a00 = *(const uint4*)(pA0);
        uint4 a10 = *(const uint4*)(pA0 + NCD);
        uint4 a01 = *(const uint4*)(pA0 + WW*NCD);
        uint4 a11 = *(const uint4*)(pA0 + WW*NCD + NCD);
        uint4 c00 = *(const uint4*)(pB0);
        uint4 c10 = *(const uint4*)(pB0 + NCD);
        uint4 c01 = *(const uint4*)(pB0 + WW*NCD);
        uint4 c11 = *(const uint4*)(pB0 + WW*NCD + NCD);

        __half2 s2[4], q2[4];
        #pragma unroll
        for (int k = 0; k < 4; k++) {
            __half2 r = H2OF(ur4, k);
            s2[k] = r;
            q2[k] = __hmul2(r, r);
        }
        {
            __half2 A = *(__half2*)&SWA[0], B = *(__half2*)&SWB[0];
            INTERP8H(a00, a10, a01, a11,
                     __low2half2(A), __high2half2(A),
                     __low2half2(B), __high2half2(B))
        }
        {
            __half2 A = *(__half2*)&SWA[1], B = *(__half2*)&SWB[1];
            INTERP8H(c00, c10, c01, c11,
                     __low2half2(A), __high2half2(A),
                     __low2half2(B), __high2half2(B))
        }

        __half2 acc = __hmul2(q2[0], wca2[0]);
        acc = __hfma2(__hmul2(s2[0], s2[0]), nwcb2[0], acc);
        #pragma unroll
        for (int k = 1; k < 4; k++) {
            acc = __hfma2(q2[k], wca2[k], acc);
            acc = __hfma2(__hmul2(s2[k], s2[k]), nwcb2[k], acc);
        }
        float2 af = __half22float2(acc);
        cl[d][pl] += af.x + af.y;   // unique (d,pl) per lane
    }
    __syncthreads();

    // ================== SOFTMAX + MOMENTS ==================
    if (t < 8) {
        const int plx  = t;
        const int pixo = blockIdx.x * 8 + plx;
        float m = -1e30f;
        #pragma unroll
        for (int d = 0; d < ND; d++) m = fmaxf(m, cl[d][plx]);
        float sum = 0.f, pd = 0.f, pd2 = 0.f;
        #pragma unroll
        for (int d = 0; d < ND; d++) {
            float e   = __expf(cl[d][plx] - m);
            float dvv = dvl[d][plx];
            sum += e;
            pd  = fmaf(e, dvv, pd);
            pd2 = fmaf(e, dvv*dvv, pd2);
        }
        float isum  = 1.f / sum;
        float depth = pd * isum;
        float sv    = pd2 * isum - depth*depth;
        float ev    = LAMBF * sqrtf(fmaxf(sv, 0.f));
        smax[plx]  = m;
        sisum[plx] = isum;
        out[pixo]       = depth;
        out[HWN + pixo] = ev;
    }
    __syncthreads();
    {
        const int plx  = t & 7;
        const int dd   = t >> 3;
        const int pixo = blockIdx.x * 8 + plx;
        out[2*HWN + dd*HWN + pixo] = __expf(cl[dd][plx] - smax[plx]) * sisum[plx];
    }
}

// ---------------------------------------------------------------------------
extern "C" void kernel_launch(void* const* d_in, const int* in_sizes, int n_in,
                              void* d_out, int out_size, void* d_ws, size_t ws_size,
                              hipStream_t stream) {
    const float* features = (const float*)d_in[0];   // (V,1,32,H,W)
    const float* deps     = (const float*)d_in[1];   // (V,1,8,H,W)
    const float* proj     = (const float*)d_in[2];   // (1,V,4,4)
    const float* dvals    = (const float*)d_in[3];   // (1,D,H,W)
    const float* regw     = (const float*)d_in[4];   // (1,40)

    float*  ws    = (float*)d_ws;
    float*  projw = ws;                              // 24 floats (64 reserved)
    __half* featH = (__half*)(ws + 64);              // 3*HW*32 halves
    __half* depsH = featH + (size_t)NV*HWN*NCF;      // 3*HW*8 halves

    dim3 tg(WW/32, HH, 2*NV);
    prep_k<<<tg, 256, 0, stream>>>(features, deps, proj, featH, depsH, projw);

    cost_volume_k<<<HWN/8, 256, 0, stream>>>(featH, depsH, dvals, regw, projw,
                                             (float*)d_out);
}